// Round 1
// baseline (35.082 us; speedup 1.0000x reference)
//
#include <hip/hip_runtime.h>
#include <math.h>

// DETR HungarianMatcher cost matrix on MI355X.
// C[n,m] = 5*L1(pred_box[n], tgt_box[m]) - softmax(logits[n])[label[m]] - 2*GIoU
// BS*NQ = 16000 rows, M = 1024 targets, NC = 92 classes.
// One block per row n: block softmax (92 classes) -> LDS, then each of 256
// threads emits 4 outputs (m = t + 256k), coalesced loads and stores.

#define NROWS 16000
#define NC 92
#define M_TGT 1024
#define TPB 256

__global__ __launch_bounds__(TPB) void hungarian_cost_kernel(
    const float* __restrict__ logits,   // [NROWS, NC]
    const float* __restrict__ pboxes,   // [NROWS, 4] cxcywh
    const float* __restrict__ tboxes,   // [M_TGT, 4] cxcywh
    const int*   __restrict__ tlabels,  // [M_TGT]
    float* __restrict__ out)            // [NROWS, M_TGT]
{
    const int n = blockIdx.x;
    const int t = threadIdx.x;
    const int lane = t & 63;
    const int wid  = t >> 6;

    __shared__ float prob[NC];
    __shared__ float red[8];

    // ---- softmax over 92 classes of row n ----
    float x = (t < NC) ? logits[n * NC + t] : -INFINITY;

    float mx = x;
    #pragma unroll
    for (int off = 32; off >= 1; off >>= 1)
        mx = fmaxf(mx, __shfl_xor(mx, off));
    if (lane == 0) red[wid] = mx;
    __syncthreads();
    mx = fmaxf(fmaxf(red[0], red[1]), fmaxf(red[2], red[3]));

    float e = (t < NC) ? __expf(x - mx) : 0.0f;
    float s = e;
    #pragma unroll
    for (int off = 32; off >= 1; off >>= 1)
        s += __shfl_xor(s, off);
    if (lane == 0) red[4 + wid] = s;   // disjoint slots from the max phase
    __syncthreads();
    s = red[4] + red[5] + red[6] + red[7];
    if (t < NC) prob[t] = e / s;
    __syncthreads();

    // ---- pred box (broadcast across block) ----
    const float4 pb = reinterpret_cast<const float4*>(pboxes)[n];
    const float ax0 = pb.x - 0.5f * pb.z;
    const float ay0 = pb.y - 0.5f * pb.w;
    const float ax1 = pb.x + 0.5f * pb.z;
    const float ay1 = pb.y + 0.5f * pb.w;
    const float area_a = (ax1 - ax0) * (ay1 - ay0);

    float* __restrict__ orow = out + (size_t)n * M_TGT;

    #pragma unroll
    for (int k = 0; k < 4; ++k) {
        const int m = t + k * TPB;
        const float4 tb = reinterpret_cast<const float4*>(tboxes)[m];
        int lbl = tlabels[m];
        lbl = (lbl < 0) ? 0 : (lbl > NC - 1 ? NC - 1 : lbl);
        const float cls = prob[lbl];

        // L1 on cxcywh
        const float cb = fabsf(pb.x - tb.x) + fabsf(pb.y - tb.y)
                       + fabsf(pb.z - tb.z) + fabsf(pb.w - tb.w);

        // GIoU on xyxy
        const float bx0 = tb.x - 0.5f * tb.z;
        const float by0 = tb.y - 0.5f * tb.w;
        const float bx1 = tb.x + 0.5f * tb.z;
        const float by1 = tb.y + 0.5f * tb.w;
        const float area_b = (bx1 - bx0) * (by1 - by0);

        const float ltx = fmaxf(ax0, bx0), lty = fmaxf(ay0, by0);
        const float rbx = fminf(ax1, bx1), rby = fminf(ay1, by1);
        const float iw = fmaxf(rbx - ltx, 0.0f), ih = fmaxf(rby - lty, 0.0f);
        const float inter = iw * ih;
        const float uni = area_a + area_b - inter;
        const float iou = inter / uni;

        const float ex0 = fminf(ax0, bx0), ey0 = fminf(ay0, by0);
        const float ex1 = fmaxf(ax1, bx1), ey1 = fmaxf(ay1, by1);
        const float ew = fmaxf(ex1 - ex0, 0.0f), eh = fmaxf(ey1 - ey0, 0.0f);
        const float ae = ew * eh;

        const float giou = iou - (ae - uni) / ae;

        orow[m] = 5.0f * cb - cls - 2.0f * giou;
    }
}

extern "C" void kernel_launch(void* const* d_in, const int* in_sizes, int n_in,
                              void* d_out, int out_size, void* d_ws, size_t ws_size,
                              hipStream_t stream) {
    const float* logits  = (const float*)d_in[0];  // [16,1000,92]
    const float* pboxes  = (const float*)d_in[1];  // [16,1000,4]
    const float* tboxes  = (const float*)d_in[2];  // [1024,4]
    const int*   tlabels = (const int*)d_in[3];    // [1024]
    float* out = (float*)d_out;                    // [16,1000,1024]

    hungarian_cost_kernel<<<NROWS, TPB, 0, stream>>>(logits, pboxes, tboxes, tlabels, out);
}

// Round 2
// 25.304 us; speedup vs baseline: 1.3864x; 1.3864x over previous
//
#include <hip/hip_runtime.h>
#include <math.h>

// DETR HungarianMatcher cost matrix on MI355X — round 2.
// C[n,m] = 5*L1 - prob[n,label[m]] - 2*GIoU, [16000 x 1024] f32 out.
// Block = 256 threads, ROWS=8 rows per block, 4 targets per thread held in
// registers (conversion/area/label amortized 8x), v_rcp_f32 instead of IEEE
// div, enclosing-box via w-sum identity (no extra min/max, no clamp).

#define NROWS 16000
#define NC 92
#define M_TGT 1024
#define TPB 256
#define ROWS 8
#define KPT 4   // targets per thread (KPT*TPB == M_TGT)

__global__ __launch_bounds__(TPB) void hungarian_cost_kernel(
    const float* __restrict__ logits,   // [NROWS, NC]
    const float* __restrict__ pboxes,   // [NROWS, 4] cxcywh
    const float* __restrict__ tboxes,   // [M_TGT, 4] cxcywh
    const int*   __restrict__ tlabels,  // [M_TGT]
    float* __restrict__ out)            // [NROWS, M_TGT]
{
    const int n0 = blockIdx.x * ROWS;
    const int t = threadIdx.x;
    const int lane = t & 63;
    const int wid  = t >> 6;

    __shared__ float prob[ROWS][NC];
    __shared__ float rowv[ROWS][12];   // ax0 ay0 ax1 ay1 area_a pcx pcy pw ph

    // ---- per-thread target contexts (registers), m = t + k*256 ----
    float tcx[KPT], tcy[KPT], twd[KPT], tht[KPT];
    float bx0[KPT], by0[KPT], bx1[KPT], by1[KPT], areab[KPT];
    int   lbl[KPT];
    #pragma unroll
    for (int k = 0; k < KPT; ++k) {
        const float4 tb = reinterpret_cast<const float4*>(tboxes)[t + k * TPB];
        tcx[k] = tb.x; tcy[k] = tb.y; twd[k] = tb.z; tht[k] = tb.w;
        bx0[k] = tb.x - 0.5f * tb.z;  by0[k] = tb.y - 0.5f * tb.w;
        bx1[k] = tb.x + 0.5f * tb.z;  by1[k] = tb.y + 0.5f * tb.w;
        areab[k] = (bx1[k] - bx0[k]) * (by1[k] - by0[k]);
        int L = tlabels[t + k * TPB];
        lbl[k] = (L < 0) ? 0 : (L > NC - 1 ? NC - 1 : L);
    }

    // ---- softmax: wave `wid` handles rows 2*wid and 2*wid+1 ----
    #pragma unroll
    for (int rr = 0; rr < 2; ++rr) {
        const int r = wid * 2 + rr;
        const float* lg = logits + (size_t)(n0 + r) * NC;
        const float x0 = lg[lane];                      // lane < 64 < NC
        const bool  hi = (lane < NC - 64);              // lanes 0..27 cover 64..91
        const float x1 = hi ? lg[64 + lane] : -INFINITY;
        float mx = fmaxf(x0, x1);
        #pragma unroll
        for (int off = 32; off >= 1; off >>= 1)
            mx = fmaxf(mx, __shfl_xor(mx, off));
        const float e0 = __expf(x0 - mx);
        const float e1 = hi ? __expf(x1 - mx) : 0.0f;
        float s = e0 + e1;
        #pragma unroll
        for (int off = 32; off >= 1; off >>= 1)
            s += __shfl_xor(s, off);
        const float rs = __builtin_amdgcn_rcpf(s);
        prob[r][lane] = e0 * rs;
        if (hi) prob[r][64 + lane] = e1 * rs;
    }

    // ---- per-row pred-box values ----
    if (t < ROWS) {
        const float4 pb = reinterpret_cast<const float4*>(pboxes)[n0 + t];
        const float ax0 = pb.x - 0.5f * pb.z, ay0 = pb.y - 0.5f * pb.w;
        const float ax1 = pb.x + 0.5f * pb.z, ay1 = pb.y + 0.5f * pb.w;
        rowv[t][0] = ax0; rowv[t][1] = ay0; rowv[t][2] = ax1; rowv[t][3] = ay1;
        rowv[t][4] = (ax1 - ax0) * (ay1 - ay0);
        rowv[t][5] = pb.x; rowv[t][6] = pb.y; rowv[t][7] = pb.z; rowv[t][8] = pb.w;
    }
    __syncthreads();

    // ---- main: 8 rows x 4 targets per thread ----
    #pragma unroll 2
    for (int r = 0; r < ROWS; ++r) {
        const float ax0 = rowv[r][0], ay0 = rowv[r][1];
        const float ax1 = rowv[r][2], ay1 = rowv[r][3];
        const float area_a = rowv[r][4];
        const float pcx = rowv[r][5], pcy = rowv[r][6];
        const float pw  = rowv[r][7], ph  = rowv[r][8];
        float* __restrict__ orow = out + (size_t)(n0 + r) * M_TGT + t;
        #pragma unroll
        for (int k = 0; k < KPT; ++k) {
            const float cls = prob[r][lbl[k]];
            const float cb = fabsf(pcx - tcx[k]) + fabsf(pcy - tcy[k])
                           + fabsf(pw - twd[k]) + fabsf(ph - tht[k]);
            // unclamped intersection extents
            const float iwu = fminf(ax1, bx1[k]) - fmaxf(ax0, bx0[k]);
            const float ihu = fminf(ay1, by1[k]) - fmaxf(ay0, by0[k]);
            const float inter = fmaxf(iwu, 0.0f) * fmaxf(ihu, 0.0f);
            const float uni = area_a + areab[k] - inter;
            // enclosing box via identity: max(a1,b1)-min(a0,b0) = wa+wb-iwu
            const float ew = pw + twd[k] - iwu;
            const float eh = ph + tht[k] - ihu;
            const float ae = ew * eh;
            const float iou  = inter * __builtin_amdgcn_rcpf(uni);
            const float covg = uni   * __builtin_amdgcn_rcpf(ae);
            // cost = 5*cb - cls - 2*(iou + covg - 1)
            orow[k * TPB] = 5.0f * cb - cls - 2.0f * iou - 2.0f * covg + 2.0f;
        }
    }
}

extern "C" void kernel_launch(void* const* d_in, const int* in_sizes, int n_in,
                              void* d_out, int out_size, void* d_ws, size_t ws_size,
                              hipStream_t stream) {
    const float* logits  = (const float*)d_in[0];  // [16,1000,92]
    const float* pboxes  = (const float*)d_in[1];  // [16,1000,4]
    const float* tboxes  = (const float*)d_in[2];  // [1024,4]
    const int*   tlabels = (const int*)d_in[3];    // [1024]
    float* out = (float*)d_out;                    // [16,1000,1024]

    hungarian_cost_kernel<<<NROWS / ROWS, TPB, 0, stream>>>(
        logits, pboxes, tboxes, tlabels, out);
}